// Round 7
// baseline (1512.466 us; speedup 1.0000x reference)
//
#include <hip/hip_runtime.h>
#include <hip/hip_cooperative_groups.h>

// MaxCutScoreNet: 12-layer delta-GCN + MLP head on N=50000 nodes, E=1.6M edges.
// R17: partition-major "bucket-row" space. br=(r&7)*6272+(r>>3); edge cols
//      PRE-MAPPED (u16, PAD_N=50176<65536); p = work&7 -> XCD-local ecw slice.
// R21: build = partitioned + LDS ballot-compaction (XCD-merged ecw writes AND
//      dense full-wave atomics) + gemm0 front works. 92us, 455us total.
// R22: cooperative mega-kernel (16 -> 2 dispatches). FAILED: absmax == max|ref|
//      => kernel never ran. Diagnosis: hard-coded grid 1536 (6 blk/CU) likely
//      exceeded max co-resident blocks -> hipErrorCooperativeLaunchTooLarge,
//      unchecked.
// R23: same fusion, robust launch: (a) occupancy QUERY sizes the coop grid
//      (multiple of 8; all phases grid-stride), (b) launch_bounds(256,4),
//      (c) return value CHECKED with full fallback to the R21 15-dispatch
//      sequence built from the SAME phase functions.
// R24: identical resubmit of R23 (previous round died to GPU acquisition
//      timeout -- no kernel execution, no new evidence).

namespace cg = cooperative_groups;

constexpr int kN = 50000;
constexpr int kE = 1600000;
constexpr float kSelfW = -1.0f;   // 1 - DELTA, DELTA = 2.0
constexpr int kCAP = 72;          // bucket capacity; P(Poisson(32) >= 72) ~ 1e-8
constexpr int PAD_N = 50176;      // 8 * 6272
constexpr int kPROWS = PAD_N / 8; // 6272 bucket rows per partition
constexpr int E4  = kE / 4;       // 400000 v4-groups
constexpr int E8B = (E4 + 511) / 512;  // 782 chunks of 2048 edges
constexpr int NBG = (kN + 255) / 256;  // 196 gemm0 works
constexpr int NW_BUILD = NBG + 8 * E8B;  // 6452 build-phase works
constexpr int NW_DEG = PAD_N / 4;  // 12544
constexpr int SB32 = PAD_N / 8;    // 6272
constexpr int SB16 = PAD_N / 16;   // 3136
constexpr int SB8  = PAD_N / 32;   // 1568
constexpr int GRID_CAP = 1536;     // upper cap on coop grid (mult of 8)
constexpr int kCUs = 256;          // MI355X

typedef int      v4i __attribute__((ext_vector_type(4)));
typedef float    v4f __attribute__((ext_vector_type(4)));
typedef _Float16 h8v __attribute__((ext_vector_type(8)));

struct MegaArgs {
  const int* src; const int* dst; const float* ew;
  int* cnt; unsigned* ecw;
  const float* X; const float* Weff; const float* beff;
  _Float16* B16; _Float16* C16;
  float* dinv;
  const float* bc[12]; const float* Wc[12];
  const float* Wm0; const float* bm0; const float* Wm1; const float* bm1;
  const float* Wf; const float* bf;
  float* out;
};

__device__ __forceinline__ int rowmap(int r) {  // original row -> bucket row
  return (r & 7) * kPROWS + (r >> 3);
}
__device__ __forceinline__ unsigned packcw(int colMapped, float w) {
  _Float16 h = (_Float16)w;
  unsigned short u;
  __builtin_memcpy(&u, &h, 2);
  return (unsigned)(unsigned short)colMapped | ((unsigned)u << 16);
}
__device__ __forceinline__ float unpw(unsigned e) {
  unsigned short u = (unsigned short)(e >> 16);
  _Float16 h;
  __builtin_memcpy(&h, &u, 2);
  return (float)h;
}
__device__ __forceinline__ unsigned pack2h(float a, float b) {
  _Float16 ha = (_Float16)a, hb = (_Float16)b;
  unsigned short ua, ub;
  __builtin_memcpy(&ua, &ha, 2);
  __builtin_memcpy(&ub, &hb, 2);
  return (unsigned)ua | ((unsigned)ub << 16);
}
__device__ __forceinline__ float fast_tanh(float x) {
  float t = __expf(2.0f * x);
  float r = __builtin_amdgcn_rcpf(t + 1.0f);
  return 1.0f - 2.0f * r;
}

// ------- prep: zero cnt (49x1024 = PAD_N exactly) + fold Weff/beff ---------
__global__ __launch_bounds__(256)
void prep(int* __restrict__ cnt, const float* __restrict__ Wi,
          const float* __restrict__ bi, const float* __restrict__ Wc0,
          float* __restrict__ Weff, float* __restrict__ beff) {
  if (blockIdx.x < 49) {
    int i = blockIdx.x * 1024 + threadIdx.x * 4;
    *reinterpret_cast<int4*>(cnt + i) = make_int4(0, 0, 0, 0);
  } else {
    int idx = (blockIdx.x - 49) * 256 + threadIdx.x;
    if (idx >= 129 * 32) return;
    int r = idx >> 5, j = idx & 31;
    float acc = 0.0f;
    if (r < 128) {
      for (int k = 0; k < 128; ++k) acc += Wi[r * 128 + k] * Wc0[k * 32 + j];
      Weff[r * 32 + j] = acc;
    } else {
      for (int k = 0; k < 128; ++k) acc += bi[k] * Wc0[k * 32 + j];
      beff[j] = acc;
    }
  }
}

// ---- phase: gemm0 front works + partitioned compacted count/scatter -------
__device__ __forceinline__ void build_phase(const MegaArgs& A, unsigned* s_buf,
                                            int grid) {
  for (int w = blockIdx.x; w < NW_BUILD; w += grid) {
    if (w < NBG) {
      // gemm0: B16[rowmap(row)] = x[row] @ Weff + beff
      float* smem = reinterpret_cast<float*>(s_buf);
      for (int idx = threadIdx.x; idx < 128 * 32; idx += 256) {
        int j = idx >> 7, k = idx & 127;
        smem[j * 128 + k] = A.Weff[k * 32 + j];   // stage transposed
      }
      if (threadIdx.x < 32) smem[4096 + threadIdx.x] = A.beff[threadIdx.x];
      __syncthreads();
      int row = w * 256 + threadIdx.x;
      if (row < kN) {
        float acc[32];
#pragma unroll
        for (int j = 0; j < 32; ++j) acc[j] = smem[4096 + j];
        const float4* xr = reinterpret_cast<const float4*>(A.X + (size_t)row * 128);
        const float4* Ws4 = reinterpret_cast<const float4*>(smem);
        for (int k4 = 0; k4 < 32; ++k4) {
          float4 a = xr[k4];
#pragma unroll
          for (int j = 0; j < 32; ++j) {
            float4 wv = Ws4[j * 32 + k4];
            acc[j] += a.x * wv.x + a.y * wv.y + a.z * wv.z + a.w * wv.w;
          }
        }
        h8v* yr = reinterpret_cast<h8v*>(A.B16 + (size_t)rowmap(row) * 32);
#pragma unroll
        for (int j8 = 0; j8 < 4; ++j8) {
          h8v v;
#pragma unroll
          for (int q = 0; q < 8; ++q) v[q] = (_Float16)acc[8 * j8 + q];
          yr[j8] = v;
        }
      }
      __syncthreads();   // smem reuse barrier before next iteration
    } else {
      // partitioned build: p = w&7 (== XCD residue when grid % 8 == 0)
      unsigned*       s_cw = s_buf;                                        // [2048]
      unsigned short* s_br = reinterpret_cast<unsigned short*>(s_buf + 2048); // [2048]
      int*            s_cnt = reinterpret_cast<int*>(s_buf + 3072);
      if (threadIdx.x == 0) *s_cnt = 0;
      __syncthreads();
      int p = w & 7;
      int chunk = (w - NBG) >> 3;
      int lane = threadIdx.x & 63;
      int i0 = chunk * 512 + threadIdx.x;
      int i1 = i0 + 256;
      v4i svA = {0,0,0,0}, dvA = {-1,-1,-1,-1};
      v4i svB = {0,0,0,0}, dvB = {-1,-1,-1,-1};
      v4f wvA = {0,0,0,0}, wvB = {0,0,0,0};
      bool vA = i0 < E4, vB = i1 < E4;
      if (vA) {
        svA = reinterpret_cast<const v4i*>(A.src)[i0];
        dvA = reinterpret_cast<const v4i*>(A.dst)[i0];
        wvA = reinterpret_cast<const v4f*>(A.ew)[i0];
      }
      if (vB) {
        svB = reinterpret_cast<const v4i*>(A.src)[i1];
        dvB = reinterpret_cast<const v4i*>(A.dst)[i1];
        wvB = reinterpret_cast<const v4f*>(A.ew)[i1];
      }
#pragma unroll
      for (int g = 0; g < 2; ++g) {
        v4i sv = g ? svB : svA;
        v4i dv = g ? dvB : dvA;
        v4f wv = g ? wvB : wvA;
        bool valid = g ? vB : vA;
#pragma unroll
        for (int c = 0; c < 4; ++c) {
          bool keep = valid && ((dv[c] & 7) == p);
          unsigned long long mask = __ballot(keep);
          int base = 0;
          int nb = __popcll(mask);
          if (lane == 0 && nb) base = atomicAdd(s_cnt, nb);   // LDS atomic
          base = __shfl(base, 0, 64);
          if (keep) {
            int pos = base + __popcll(mask & ((1ull << lane) - 1ull));
            s_cw[pos] = packcw(rowmap(sv[c]), wv[c]);
            s_br[pos] = (unsigned short)(dv[c] >> 3);
          }
        }
      }
      __syncthreads();
      int m = *s_cnt;                    // ~256 +- 16
      for (int t = threadIdx.x; t < m; t += 256) {
        int br = p * kPROWS + s_br[t];
        int r = atomicAdd(&A.cnt[br], 1);  // dense full-wave atomics
        if (r < kCAP) A.ecw[(size_t)br * kCAP + r] = s_cw[t];  // XCD-local
      }
      __syncthreads();   // smem reuse barrier before next iteration
    }
  }
}

// ------- phase: wave-per-bucket-row deg sum -> dinv[br] --------------------
__device__ __forceinline__ void deg_phase(const MegaArgs& A, int grid) {
  int lane = threadIdx.x & 63;
  int wid = threadIdx.x >> 6;
  for (int w = blockIdx.x; w < NW_DEG; w += grid) {
    int br = w * 4 + wid;
    int deg = min(A.cnt[br], kCAP);
    size_t base = (size_t)br * kCAP;
    float d = 0.0f;
    for (int i = lane; i < deg; i += 64) d += unpw(A.ecw[base + i]);
#pragma unroll
    for (int off = 32; off > 0; off >>= 1) d += __shfl_xor(d, off, 64);
    if (lane == 0) A.dinv[br] = (d > 0.0f) ? rsqrtf(fmaxf(d, 1e-12f)) : 0.0f;
  }
}

// -- phase: w = 2*dinv[br]*dinv[colMapped]*ew + zero-pad slots --------------
__device__ __forceinline__ void wscale_phase(const MegaArgs& A, int grid) {
  int lane = threadIdx.x & 63;
  int wid = threadIdx.x >> 6;
  for (int w = blockIdx.x; w < NW_DEG; w += grid) {
    int br = w * 4 + wid;
    int deg = min(A.cnt[br], kCAP);
    size_t base = (size_t)br * kCAP;
    float dr = 2.0f * A.dinv[br];
    for (int i = lane; i < kCAP; i += 64) {
      if (i < deg) {
        unsigned e = A.ecw[base + i];
        int cm = e & 0xFFFFu;
        A.ecw[base + i] = packcw(cm, dr * A.dinv[cm] * unpw(e));
      } else {
        A.ecw[base + i] = 0u;   // colMapped=0, w=0 sentinel
      }
    }
  }
}

// ------ phase: fused SpMM + self + bias + tanh (+ next GEMM or MLP head) ---
template <int DOUT, int DNEXT, bool FINAL>
__device__ __forceinline__ void spmm_phase(const _Float16* HW, const float* b,
                                           const float* Wn, void* Out,
                                           const MegaArgs& A, float* smem,
                                           int nwork, int grid) {
  constexpr int R = 64 / DOUT;       // rows per wave (2 / 4 / 8)
  constexpr int W = DOUT;            // lanes per row
  constexpr int L = DOUT / 8;        // lanes per edge (4 / 2 / 1)
  constexpr int S = 8;               // subs per row
  constexpr int WST = DNEXT + 1;
  constexpr int JPT = (DNEXT > 0) ? (DNEXT / S) : 1;   // cols per lane
  if constexpr (DNEXT > 0) {
    for (int idx = threadIdx.x; idx < DOUT * DNEXT; idx += 256) {
      int k = idx / DNEXT, j = idx - k * DNEXT;
      smem[k * WST + j] = Wn[idx];
    }
  }
  if constexpr (FINAL) {
    int t = threadIdx.x;
    if (t < 128) smem[t] = A.Wm0[t];          // w0: 8x16
    if (t < 256) smem[128 + t] = A.Wm1[t];    // w1: 16x16
    if (t < 16) {
      smem[384 + t] = A.bm0[t];
      smem[400 + t] = A.bm1[t];
      smem[416 + t] = A.Wf[t];
    }
    if (t == 0) smem[432] = A.bf[0];
  }
  __syncthreads();
  int lane = threadIdx.x & 63;
  int wid = threadIdx.x >> 6;
  int g = lane / W;                  // row-group (0..R-1)
  int gl = lane - g * W;
  int ch8 = gl & (L - 1);
  int sub = gl / L;                  // 0..7
  const h8v* HW8 = reinterpret_cast<const h8v*>(HW);
  for (int w = blockIdx.x; w < nwork; w += grid) {
    int p = w & 7;                   // partition (XCD-local: grid % 8 == 0)
    int q = w >> 3;
    int brLocal = q * (4 * R) + wid * R + g;
    int br = p * kPROWS + brLocal;   // bucket row == hw row index
    int deg = min(A.cnt[br], kCAP);
    const uint4* ecw4 = reinterpret_cast<const uint4*>(A.ecw + (size_t)br * kCAP);
    uint4 ea = ecw4[sub];
    uint4 eb = ecw4[8 + sub];
    h8v a0 = HW8[(size_t)(ea.x & 0xFFFFu) * L + ch8];
    h8v a1 = HW8[(size_t)(ea.y & 0xFFFFu) * L + ch8];
    h8v a2 = HW8[(size_t)(ea.z & 0xFFFFu) * L + ch8];
    h8v a3 = HW8[(size_t)(ea.w & 0xFFFFu) * L + ch8];
    h8v b0 = HW8[(size_t)(eb.x & 0xFFFFu) * L + ch8];
    h8v b1 = HW8[(size_t)(eb.y & 0xFFFFu) * L + ch8];
    h8v b2 = HW8[(size_t)(eb.z & 0xFFFFu) * L + ch8];
    h8v b3 = HW8[(size_t)(eb.w & 0xFFFFu) * L + ch8];
    float wa0 = unpw(ea.x), wa1 = unpw(ea.y), wa2 = unpw(ea.z), wa3 = unpw(ea.w);
    float wb0 = unpw(eb.x), wb1 = unpw(eb.y), wb2 = unpw(eb.z), wb3 = unpw(eb.w);
    float acc[8];
#pragma unroll
    for (int q8 = 0; q8 < 8; ++q8)
      acc[q8] = wa0 * (float)a0[q8] + wa1 * (float)a1[q8] +
                wa2 * (float)a2[q8] + wa3 * (float)a3[q8] +
                wb0 * (float)b0[q8] + wb1 * (float)b1[q8] +
                wb2 * (float)b2[q8] + wb3 * (float)b3[q8];
    if (deg > 64) {                  // rare tail: slots 64..71 (subs 0,1)
      if (sub < 2) {
        uint4 et = ecw4[16 + sub];
        h8v t0 = HW8[(size_t)(et.x & 0xFFFFu) * L + ch8];
        h8v t1 = HW8[(size_t)(et.y & 0xFFFFu) * L + ch8];
        h8v t2 = HW8[(size_t)(et.z & 0xFFFFu) * L + ch8];
        h8v t3 = HW8[(size_t)(et.w & 0xFFFFu) * L + ch8];
        float u0 = unpw(et.x), u1 = unpw(et.y), u2 = unpw(et.z), u3 = unpw(et.w);
#pragma unroll
        for (int q8 = 0; q8 < 8; ++q8)
          acc[q8] += u0 * (float)t0[q8] + u1 * (float)t1[q8] +
                     u2 * (float)t2[q8] + u3 * (float)t3[q8];
      }
    }
#pragma unroll
    for (int off = W / 2; off >= L; off >>= 1) {
#pragma unroll
      for (int q8 = 0; q8 < 8; ++q8) acc[q8] += __shfl_xor(acc[q8], off, 64);
    }
    int krow = 8 * ch8;
    h8v hsv = HW8[(size_t)br * L + ch8];
    float h[8];
#pragma unroll
    for (int q8 = 0; q8 < 8; ++q8)
      h[q8] = fast_tanh(acc[q8] + kSelfW * (float)hsv[q8] + b[krow + q8]);
    if constexpr (FINAL) {
      int row = (brLocal << 3) | p;  // inverse map for output
      if (gl == 0 && row < kN) {
        float y0[16];
#pragma unroll
        for (int j = 0; j < 16; ++j) {
          float v = smem[384 + j];
#pragma unroll
          for (int k = 0; k < 8; ++k) v += h[k] * smem[k * 16 + j];
          y0[j] = fmaxf(v, 0.0f);
        }
        float y1[16];
#pragma unroll
        for (int j = 0; j < 16; ++j) {
          float v = smem[400 + j];
#pragma unroll
          for (int k = 0; k < 16; ++k) v += y0[k] * smem[128 + k * 16 + j];
          y1[j] = fmaxf(v, 0.0f);
        }
        float z = smem[432];
#pragma unroll
        for (int k = 0; k < 16; ++k) z += y1[k] * smem[416 + k];
        reinterpret_cast<float*>(Out)[row] = fast_tanh(z);
      }
    } else {
      float pj[JPT];
      int jbase = sub * JPT;
#pragma unroll
      for (int jj = 0; jj < JPT; ++jj) {
        int j = jbase + jj;
        float v = 0.0f;
#pragma unroll
        for (int q8 = 0; q8 < 8; ++q8) v += h[q8] * smem[(krow + q8) * WST + j];
        pj[jj] = v;
      }
#pragma unroll
      for (int off = 1; off < L; off <<= 1) {
#pragma unroll
        for (int jj = 0; jj < JPT; ++jj) pj[jj] += __shfl_xor(pj[jj], off, 64);
      }
      if (ch8 == 0) {                // pad rows write into pad hw slots (ok)
        _Float16* op = reinterpret_cast<_Float16*>(Out) + (size_t)br * DNEXT + jbase;
        if constexpr (JPT == 4) {
          uint2 u = make_uint2(pack2h(pj[0], pj[1]), pack2h(pj[2], pj[3]));
          *reinterpret_cast<uint2*>(op) = u;
        } else if constexpr (JPT == 2) {
          *reinterpret_cast<unsigned*>(op) = pack2h(pj[0], pj[1]);
        } else {
          op[0] = (_Float16)pj[0];
        }
      }
    }
  }
}

// ---------------- cooperative mega-kernel ----------------
__global__ __launch_bounds__(256, 4)
void mega(MegaArgs A) {
  __shared__ unsigned s_buf[4128];   // 16.5 KB shared by all phases
  cg::grid_group gg = cg::this_grid();
  float* smemF = reinterpret_cast<float*>(s_buf);
  const int grid = gridDim.x;

  build_phase(A, s_buf, grid);                                   gg.sync();
  deg_phase(A, grid);                                            gg.sync();
  wscale_phase(A, grid);                                         gg.sync();
  spmm_phase<32, 32, false>(A.B16, A.bc[0], A.Wc[1], A.C16, A, smemF, SB32, grid); gg.sync();
  spmm_phase<32, 32, false>(A.C16, A.bc[1], A.Wc[2], A.B16, A, smemF, SB32, grid); gg.sync();
  spmm_phase<32, 32, false>(A.B16, A.bc[2], A.Wc[3], A.C16, A, smemF, SB32, grid); gg.sync();
  spmm_phase<32, 16, false>(A.C16, A.bc[3], A.Wc[4], A.B16, A, smemF, SB32, grid); gg.sync();
  spmm_phase<16, 16, false>(A.B16, A.bc[4], A.Wc[5], A.C16, A, smemF, SB16, grid); gg.sync();
  spmm_phase<16, 16, false>(A.C16, A.bc[5], A.Wc[6], A.B16, A, smemF, SB16, grid); gg.sync();
  spmm_phase<16, 16, false>(A.B16, A.bc[6], A.Wc[7], A.C16, A, smemF, SB16, grid); gg.sync();
  spmm_phase<16,  8, false>(A.C16, A.bc[7], A.Wc[8], A.B16, A, smemF, SB16, grid); gg.sync();
  spmm_phase<8,   8, false>(A.B16, A.bc[8], A.Wc[9], A.C16, A, smemF, SB8,  grid); gg.sync();
  spmm_phase<8,   8, false>(A.C16, A.bc[9], A.Wc[10], A.B16, A, smemF, SB8, grid); gg.sync();
  spmm_phase<8,   8, false>(A.B16, A.bc[10], A.Wc[11], A.C16, A, smemF, SB8, grid); gg.sync();
  spmm_phase<8,   0, true >(A.C16, A.bc[11], nullptr, A.out, A, smemF, SB8, grid);
}

// ---------------- standalone fallback kernels (same phase code) ------------
__global__ __launch_bounds__(256)
void k_build(MegaArgs A) {
  __shared__ unsigned s_buf[4128];
  build_phase(A, s_buf, gridDim.x);
}
__global__ __launch_bounds__(256)
void k_deg(MegaArgs A) { deg_phase(A, gridDim.x); }
__global__ __launch_bounds__(256)
void k_wscale(MegaArgs A) { wscale_phase(A, gridDim.x); }
template <int DOUT, int DNEXT, bool FINAL>
__global__ __launch_bounds__(256)
void k_spmm(MegaArgs A, const _Float16* HW, const float* b,
            const float* Wn, void* Out, int nwork) {
  __shared__ float smem[4128];
  spmm_phase<DOUT, DNEXT, FINAL>(HW, b, Wn, Out, A, smem, nwork, gridDim.x);
}

// ---------------- launch ----------------
extern "C" void kernel_launch(void* const* d_in, const int* in_sizes, int n_in,
                              void* d_out, int out_size, void* d_ws, size_t ws_size,
                              hipStream_t stream) {
  const float* x   = (const float*)d_in[0];
  const int*  eidx = (const int*)d_in[1];
  const float* ew  = (const float*)d_in[2];
  const float* Wi  = (const float*)d_in[3];
  const float* bi  = (const float*)d_in[4];

  float* wsf = (float*)d_ws;
  size_t off = 0;
  float*     dinv = wsf + off;              off += PAD_N;
  float*     Weff = wsf + off;              off += 128 * 32;
  float*     beff = wsf + off;              off += 64;
  int*       cnt  = (int*)(wsf + off);      off += PAD_N;
  unsigned*  ecw  = (unsigned*)(wsf + off); off += (size_t)PAD_N * kCAP;  // 14.45 MB
  _Float16*  B16  = (_Float16*)(wsf + off); off += (size_t)PAD_N * 16;
  _Float16*  C16  = (_Float16*)(wsf + off); off += (size_t)PAD_N * 16;

  MegaArgs A;
  A.src = eidx;            // edge_index[0]
  A.dst = eidx + kE;       // edge_index[1]
  A.ew  = ew;
  A.cnt = cnt; A.ecw = ecw;
  A.X = x; A.Weff = Weff; A.beff = beff;
  A.B16 = B16; A.C16 = C16;
  A.dinv = dinv;
  for (int i = 0; i < 12; ++i) {
    A.Wc[i] = (const float*)d_in[5 + 2 * i];
    A.bc[i] = (const float*)d_in[6 + 2 * i];
  }
  A.Wm0 = (const float*)d_in[29]; A.bm0 = (const float*)d_in[30];
  A.Wm1 = (const float*)d_in[31]; A.bm1 = (const float*)d_in[32];
  A.Wf  = (const float*)d_in[33]; A.bf  = (const float*)d_in[34];
  A.out = (float*)d_out;

  prep<<<66, 256, 0, stream>>>(cnt, Wi, bi, (const float*)d_in[5], Weff, beff);

  // --- cooperative attempt: occupancy-sized grid, checked launch ---
  bool coop_ok = false;
  int nb = 0;
  if (hipOccupancyMaxActiveBlocksPerMultiprocessor(&nb, mega, 256, 0) ==
          hipSuccess && nb > 0) {
    int grid = nb * kCUs;
    if (grid > GRID_CAP) grid = GRID_CAP;
    grid &= ~7;                       // partition mapping needs grid % 8 == 0
    if (grid >= 8) {
      void* kargs[] = { (void*)&A };
      if (hipLaunchCooperativeKernel(mega, dim3(grid), dim3(256), kargs, 0,
                                     stream) == hipSuccess)
        coop_ok = true;
    }
  }
  if (coop_ok) return;

  // --- fallback: R21-equivalent 15-dispatch sequence (same phase code) ---
  k_build<<<NW_BUILD, 256, 0, stream>>>(A);
  k_deg<<<NW_DEG, 256, 0, stream>>>(A);
  k_wscale<<<NW_DEG, 256, 0, stream>>>(A);
  k_spmm<32, 32, false><<<SB32, 256, 0, stream>>>(A, A.B16, A.bc[0], A.Wc[1], A.C16, SB32);
  k_spmm<32, 32, false><<<SB32, 256, 0, stream>>>(A, A.C16, A.bc[1], A.Wc[2], A.B16, SB32);
  k_spmm<32, 32, false><<<SB32, 256, 0, stream>>>(A, A.B16, A.bc[2], A.Wc[3], A.C16, SB32);
  k_spmm<32, 16, false><<<SB32, 256, 0, stream>>>(A, A.C16, A.bc[3], A.Wc[4], A.B16, SB32);
  k_spmm<16, 16, false><<<SB16, 256, 0, stream>>>(A, A.B16, A.bc[4], A.Wc[5], A.C16, SB16);
  k_spmm<16, 16, false><<<SB16, 256, 0, stream>>>(A, A.C16, A.bc[5], A.Wc[6], A.B16, SB16);
  k_spmm<16, 16, false><<<SB16, 256, 0, stream>>>(A, A.B16, A.bc[6], A.Wc[7], A.C16, SB16);
  k_spmm<16,  8, false><<<SB16, 256, 0, stream>>>(A, A.C16, A.bc[7], A.Wc[8], A.B16, SB16);
  k_spmm<8,   8, false><<<SB8, 256, 0, stream>>>(A, A.B16, A.bc[8], A.Wc[9], A.C16, SB8);
  k_spmm<8,   8, false><<<SB8, 256, 0, stream>>>(A, A.C16, A.bc[9], A.Wc[10], A.B16, SB8);
  k_spmm<8,   8, false><<<SB8, 256, 0, stream>>>(A, A.B16, A.bc[10], A.Wc[11], A.C16, SB8);
  k_spmm<8,   0, true ><<<SB8, 256, 0, stream>>>(A, A.C16, A.bc[11], nullptr, A.out, SB8);
}

// Round 10
// 448.361 us; speedup vs baseline: 3.3733x; 3.3733x over previous
//
#include <hip/hip_runtime.h>

// MaxCutScoreNet: 12-layer delta-GCN + MLP head on N=50000 nodes, E=1.6M edges.
// R17: partition-major "bucket-row" space. br=(r&7)*6272+(r>>3); edge cols
//      PRE-MAPPED (u16, PAD_N=50176<65536); p=blockIdx&7 -> XCD-local ecw slice.
// R21: build = partitioned + LDS ballot-compaction (XCD-merged ecw writes AND
//      dense full-wave atomics) + gemm0 front blocks. 92us build, 455us total.
// R22-R24: cooperative mega-kernel REFUTED: 1512us. grid.sync() spin-poll
//      across 8 non-coherent L2s costs ~140us/sync (FETCH+WRITE ballooned to
//      1GB, all pipes idle). Dispatch boundaries (~5-10us) are 10x cheaper
//      than coop syncs on this platform -> split pipeline is correct.
// R25: R21 structure restored + DEGREE-GATED HALF-SKIP in spmm: mean deg=32,
//      so ~54% of rows (Poisson) have deg<=32 and skip the second 32-slot
//      half (32B ecw + 4x16B gathers) entirely; >64 tail nested inside.
//      Math exact: skipped slots are w=0 sentinels (zeroed by wscale).
// R27: identical resubmit of R25 (third GPU acquisition timeout -- kernel
//      has never executed; no new evidence).

constexpr int kN = 50000;
constexpr int kE = 1600000;
constexpr float kSelfW = -1.0f;   // 1 - DELTA, DELTA = 2.0
constexpr int kCAP = 72;          // bucket capacity; P(Poisson(32) >= 72) ~ 1e-8
constexpr int PAD_N = 50176;      // 8 * 6272
constexpr int kPROWS = PAD_N / 8; // 6272 bucket rows per partition
constexpr int E4  = kE / 4;       // 400000 v4-groups
constexpr int E8B = (E4 + 511) / 512;  // 782 chunks of 2048 edges
constexpr int NBG = (kN + 255) / 256;  // 196 gemm0 blocks

typedef int      v4i __attribute__((ext_vector_type(4)));
typedef float    v4f __attribute__((ext_vector_type(4)));
typedef _Float16 h8v __attribute__((ext_vector_type(8)));

__device__ __forceinline__ int rowmap(int r) {  // original row -> bucket row
  return (r & 7) * kPROWS + (r >> 3);
}
__device__ __forceinline__ unsigned packcw(int colMapped, float w) {
  _Float16 h = (_Float16)w;
  unsigned short u;
  __builtin_memcpy(&u, &h, 2);
  return (unsigned)(unsigned short)colMapped | ((unsigned)u << 16);
}
__device__ __forceinline__ float unpw(unsigned e) {
  unsigned short u = (unsigned short)(e >> 16);
  _Float16 h;
  __builtin_memcpy(&h, &u, 2);
  return (float)h;
}
__device__ __forceinline__ unsigned pack2h(float a, float b) {
  _Float16 ha = (_Float16)a, hb = (_Float16)b;
  unsigned short ua, ub;
  __builtin_memcpy(&ua, &ha, 2);
  __builtin_memcpy(&ub, &hb, 2);
  return (unsigned)ua | ((unsigned)ub << 16);
}
__device__ __forceinline__ float fast_tanh(float x) {
  float t = __expf(2.0f * x);
  float r = __builtin_amdgcn_rcpf(t + 1.0f);
  return 1.0f - 2.0f * r;
}

// ------- prep: zero cnt (49x1024 = PAD_N exactly) + fold Weff/beff ---------
__global__ __launch_bounds__(256)
void prep(int* __restrict__ cnt, const float* __restrict__ Wi,
          const float* __restrict__ bi, const float* __restrict__ Wc0,
          float* __restrict__ Weff, float* __restrict__ beff) {
  if (blockIdx.x < 49) {
    int i = blockIdx.x * 1024 + threadIdx.x * 4;
    *reinterpret_cast<int4*>(cnt + i) = make_int4(0, 0, 0, 0);
  } else {
    int idx = (blockIdx.x - 49) * 256 + threadIdx.x;
    if (idx >= 129 * 32) return;
    int r = idx >> 5, j = idx & 31;
    float acc = 0.0f;
    if (r < 128) {
      for (int k = 0; k < 128; ++k) acc += Wi[r * 128 + k] * Wc0[k * 32 + j];
      Weff[r * 32 + j] = acc;
    } else {
      for (int k = 0; k < 128; ++k) acc += bi[k] * Wc0[k * 32 + j];
      beff[j] = acc;
    }
  }
}

// -- merged: gemm0 front blocks + partitioned compacted count/scatter -------
// Blocks [0, NBG): gemm0 (B16[rowmap(row)] = x[row] @ Weff + beff) -- front
//   of grid so it overlaps the atomic wall from dispatch start.
// Blocks [NBG, NBG+8*E8B): build. p=blockIdx&7 (== XCD residue under
//   round-robin dispatch -> ecw stores merge in one XCD's L2); chunk of 2048
//   edges ballot-compacted to ~256 matching edges in LDS, then FULL waves
//   issue dense global atomics + XCD-local ecw stores.
__global__ __launch_bounds__(256)
void build_cnt_gemm0(const int* __restrict__ src, const int* __restrict__ dst,
                     const float* __restrict__ ew, int* __restrict__ cnt,
                     unsigned* __restrict__ ecw,
                     const float* __restrict__ X,
                     const float* __restrict__ Weff,
                     const float* __restrict__ beff,
                     _Float16* __restrict__ Y, int e4, int n) {
  __shared__ unsigned s_buf[4128];   // 16.5KB; aliased by both branches
  if (blockIdx.x < NBG) {
    // ---------------- gemm0 front blocks ----------------
    float* smem = reinterpret_cast<float*>(s_buf);
    for (int idx = threadIdx.x; idx < 128 * 32; idx += 256) {
      int j = idx >> 7, k = idx & 127;
      smem[j * 128 + k] = Weff[k * 32 + j];   // stage transposed
    }
    if (threadIdx.x < 32) smem[4096 + threadIdx.x] = beff[threadIdx.x];
    __syncthreads();
    int row = blockIdx.x * 256 + threadIdx.x;
    if (row >= n) return;
    float acc[32];
#pragma unroll
    for (int j = 0; j < 32; ++j) acc[j] = smem[4096 + j];
    const float4* xr = reinterpret_cast<const float4*>(X + (size_t)row * 128);
    const float4* Ws4 = reinterpret_cast<const float4*>(smem);
    for (int k4 = 0; k4 < 32; ++k4) {
      float4 a = xr[k4];
#pragma unroll
      for (int j = 0; j < 32; ++j) {
        float4 wv = Ws4[j * 32 + k4];
        acc[j] += a.x * wv.x + a.y * wv.y + a.z * wv.z + a.w * wv.w;
      }
    }
    h8v* yr = reinterpret_cast<h8v*>(Y + (size_t)rowmap(row) * 32);
#pragma unroll
    for (int j8 = 0; j8 < 4; ++j8) {
      h8v v;
#pragma unroll
      for (int q = 0; q < 8; ++q) v[q] = (_Float16)acc[8 * j8 + q];
      yr[j8] = v;
    }
    return;
  }
  // ---------------- partitioned build blocks ----------------
  unsigned*       s_cw = s_buf;                                        // [2048]
  unsigned short* s_br = reinterpret_cast<unsigned short*>(s_buf + 2048); // [2048]
  int*            s_cnt = reinterpret_cast<int*>(s_buf + 3072);
  if (threadIdx.x == 0) *s_cnt = 0;
  __syncthreads();
  int b = blockIdx.x - NBG;
  int p = blockIdx.x & 7;           // partition == XCD residue (perf heuristic)
  int chunk = b >> 3;
  int lane = threadIdx.x & 63;
  int i0 = chunk * 512 + threadIdx.x;
  int i1 = i0 + 256;
  v4i svA = {0,0,0,0}, dvA = {-1,-1,-1,-1};
  v4i svB = {0,0,0,0}, dvB = {-1,-1,-1,-1};
  v4f wvA = {0,0,0,0}, wvB = {0,0,0,0};
  bool vA = i0 < e4, vB = i1 < e4;
  if (vA) {
    svA = reinterpret_cast<const v4i*>(src)[i0];
    dvA = reinterpret_cast<const v4i*>(dst)[i0];
    wvA = reinterpret_cast<const v4f*>(ew)[i0];
  }
  if (vB) {
    svB = reinterpret_cast<const v4i*>(src)[i1];
    dvB = reinterpret_cast<const v4i*>(dst)[i1];
    wvB = reinterpret_cast<const v4f*>(ew)[i1];
  }
#pragma unroll
  for (int g = 0; g < 2; ++g) {
    v4i sv = g ? svB : svA;
    v4i dv = g ? dvB : dvA;
    v4f wv = g ? wvB : wvA;
    bool valid = g ? vB : vA;
#pragma unroll
    for (int c = 0; c < 4; ++c) {
      bool keep = valid && ((dv[c] & 7) == p);
      unsigned long long mask = __ballot(keep);
      int base = 0;
      int nb = __popcll(mask);
      if (lane == 0 && nb) base = atomicAdd(s_cnt, nb);   // LDS atomic, 1/wave
      base = __shfl(base, 0, 64);
      if (keep) {
        int pos = base + __popcll(mask & ((1ull << lane) - 1ull));
        s_cw[pos] = packcw(rowmap(sv[c]), wv[c]);
        s_br[pos] = (unsigned short)(dv[c] >> 3);
      }
    }
  }
  __syncthreads();
  int m = *s_cnt;                    // ~256 +- 16
  for (int t = threadIdx.x; t < m; t += 256) {
    int br = p * kPROWS + s_br[t];
    int r = atomicAdd(&cnt[br], 1);  // dense: full waves issue 64 ops/instr
    if (r < kCAP) ecw[(size_t)br * kCAP + r] = s_cw[t];  // XCD-local slice
  }
}

// ------- wave-per-bucket-row deg sum -> dinv[br] ---------------------------
__global__ __launch_bounds__(256)
void deg_dinv_wave(const int* __restrict__ cnt, const unsigned* __restrict__ ecw,
                   float* __restrict__ dinv) {
  int lane = threadIdx.x & 63;
  int br = blockIdx.x * 4 + (threadIdx.x >> 6);
  int deg = min(cnt[br], kCAP);
  size_t base = (size_t)br * kCAP;
  float d = 0.0f;
  for (int i = lane; i < deg; i += 64) d += unpw(ecw[base + i]);
#pragma unroll
  for (int off = 32; off > 0; off >>= 1) d += __shfl_xor(d, off, 64);
  if (lane == 0) dinv[br] = (d > 0.0f) ? rsqrtf(fmaxf(d, 1e-12f)) : 0.0f;
}

// -- scale w = 2*dinv[br]*dinv[colMapped]*ew + zero-pad slots (all PAD_N) ---
__global__ __launch_bounds__(256)
void wscale_wave(const int* __restrict__ cnt, unsigned* __restrict__ ecw,
                 const float* __restrict__ dinv) {
  int lane = threadIdx.x & 63;
  int br = blockIdx.x * 4 + (threadIdx.x >> 6);
  int deg = min(cnt[br], kCAP);
  size_t base = (size_t)br * kCAP;
  float dr = 2.0f * dinv[br];
  for (int i = lane; i < kCAP; i += 64) {
    if (i < deg) {
      unsigned e = ecw[base + i];
      int cm = e & 0xFFFFu;
      ecw[base + i] = packcw(cm, dr * dinv[cm] * unpw(e));
    } else {
      ecw[base + i] = 0u;   // colMapped=0, w=0 sentinel
    }
  }
}

// ------ fused SpMM + self + bias + tanh (+ next GEMM or MLP head) ----------
// Partition-local blocks: p=blockIdx&7, q=blockIdx>>3; wave handles R
// consecutive bucket rows of partition p -> contiguous ecw + hw slices.
// R=64/DOUT rows/wave, W=DOUT lanes/row, L=DOUT/8, S=8 subs.
// R25: slots 0..31 unconditional; slots 32..63 (+rare 64..71 tail) gated on
// deg>32 -- ~54% of rows skip the whole second half (w=0 sentinels there).
template <int DOUT, int DNEXT, bool FINAL>
__global__ __launch_bounds__(256)
void spmm_fused(const _Float16* __restrict__ HW, const int* __restrict__ cnt,
                const unsigned* __restrict__ ecw, const float* __restrict__ b,
                const float* __restrict__ Wn, void* __restrict__ Out,
                const float* __restrict__ Wm0, const float* __restrict__ bm0,
                const float* __restrict__ Wm1, const float* __restrict__ bm1,
                const float* __restrict__ Wf, const float* __restrict__ bf,
                int n) {
  constexpr int R = 64 / DOUT;       // rows per wave (2 / 4 / 8)
  constexpr int W = DOUT;            // lanes per row
  constexpr int L = DOUT / 8;        // lanes per edge (4 / 2 / 1)
  constexpr int S = 8;               // subs per row
  constexpr int WST = DNEXT + 1;
  constexpr int JPT = (DNEXT > 0) ? (DNEXT / S) : 1;   // cols per lane
  __shared__ float smem[(DNEXT > 0) ? DOUT * WST : 448];
  if constexpr (DNEXT > 0) {
    for (int idx = threadIdx.x; idx < DOUT * DNEXT; idx += 256) {
      int k = idx / DNEXT, j = idx - k * DNEXT;
      smem[k * WST + j] = Wn[idx];
    }
    __syncthreads();
  }
  if constexpr (FINAL) {
    int t = threadIdx.x;
    if (t < 128) smem[t] = Wm0[t];          // w0: 8x16
    if (t < 256) smem[128 + t] = Wm1[t];    // w1: 16x16
    if (t < 16) {
      smem[384 + t] = bm0[t];
      smem[400 + t] = bm1[t];
      smem[416 + t] = Wf[t];
    }
    if (t == 0) smem[432] = bf[0];
    __syncthreads();
  }
  int lane = threadIdx.x & 63;
  int wid = threadIdx.x >> 6;
  int g = lane / W;                  // row-group (0..R-1)
  int gl = lane - g * W;
  int ch8 = gl & (L - 1);
  int sub = gl / L;                  // 0..7
  int p = blockIdx.x & 7;            // partition (XCD-local heuristic)
  int q = blockIdx.x >> 3;
  int brLocal = q * (4 * R) + wid * R + g;
  int br = p * kPROWS + brLocal;     // bucket row == hw row index
  int deg = min(cnt[br], kCAP);
  const uint4* ecw4 = reinterpret_cast<const uint4*>(ecw + (size_t)br * kCAP);
  const h8v* HW8 = reinterpret_cast<const h8v*>(HW);
  uint4 ea = ecw4[sub];
  h8v a0 = HW8[(size_t)(ea.x & 0xFFFFu) * L + ch8];
  h8v a1 = HW8[(size_t)(ea.y & 0xFFFFu) * L + ch8];
  h8v a2 = HW8[(size_t)(ea.z & 0xFFFFu) * L + ch8];
  h8v a3 = HW8[(size_t)(ea.w & 0xFFFFu) * L + ch8];
  float wa0 = unpw(ea.x), wa1 = unpw(ea.y), wa2 = unpw(ea.z), wa3 = unpw(ea.w);
  float acc[8];
#pragma unroll
  for (int q8 = 0; q8 < 8; ++q8)
    acc[q8] = wa0 * (float)a0[q8] + wa1 * (float)a1[q8] +
              wa2 * (float)a2[q8] + wa3 * (float)a3[q8];
  if (deg > 32) {                    // ~46% of rows: second 32-slot half
    uint4 eb = ecw4[8 + sub];
    h8v b0 = HW8[(size_t)(eb.x & 0xFFFFu) * L + ch8];
    h8v b1 = HW8[(size_t)(eb.y & 0xFFFFu) * L + ch8];
    h8v b2 = HW8[(size_t)(eb.z & 0xFFFFu) * L + ch8];
    h8v b3 = HW8[(size_t)(eb.w & 0xFFFFu) * L + ch8];
    float wb0 = unpw(eb.x), wb1 = unpw(eb.y), wb2 = unpw(eb.z), wb3 = unpw(eb.w);
#pragma unroll
    for (int q8 = 0; q8 < 8; ++q8)
      acc[q8] += wb0 * (float)b0[q8] + wb1 * (float)b1[q8] +
                 wb2 * (float)b2[q8] + wb3 * (float)b3[q8];
    if (deg > 64) {                  // rare tail: slots 64..71 (subs 0,1)
      if (sub < 2) {
        uint4 et = ecw4[16 + sub];
        h8v t0 = HW8[(size_t)(et.x & 0xFFFFu) * L + ch8];
        h8v t1 = HW8[(size_t)(et.y & 0xFFFFu) * L + ch8];
        h8v t2 = HW8[(size_t)(et.z & 0xFFFFu) * L + ch8];
        h8v t3 = HW8[(size_t)(et.w & 0xFFFFu) * L + ch8];
        float u0 = unpw(et.x), u1 = unpw(et.y), u2 = unpw(et.z), u3 = unpw(et.w);
#pragma unroll
        for (int q8 = 0; q8 < 8; ++q8)
          acc[q8] += u0 * (float)t0[q8] + u1 * (float)t1[q8] +
                     u2 * (float)t2[q8] + u3 * (float)t3[q8];
      }
    }
  }
#pragma unroll
  for (int off = W / 2; off >= L; off >>= 1) {
#pragma unroll
    for (int q8 = 0; q8 < 8; ++q8) acc[q8] += __shfl_xor(acc[q8], off, 64);
  }
  int krow = 8 * ch8;
  h8v hsv = HW8[(size_t)br * L + ch8];
  float h[8];
#pragma unroll
  for (int q8 = 0; q8 < 8; ++q8)
    h[q8] = fast_tanh(acc[q8] + kSelfW * (float)hsv[q8] + b[krow + q8]);
  if constexpr (FINAL) {
    int row = (brLocal << 3) | p;    // inverse map for output
    if (gl == 0 && row < n) {
      float y0[16];
#pragma unroll
      for (int j = 0; j < 16; ++j) {
        float v = smem[384 + j];
#pragma unroll
        for (int k = 0; k < 8; ++k) v += h[k] * smem[k * 16 + j];
        y0[j] = fmaxf(v, 0.0f);
      }
      float y1[16];
#pragma unroll
      for (int j = 0; j < 16; ++j) {
        float v = smem[400 + j];
#pragma unroll
        for (int k = 0; k < 16; ++k) v += y0[k] * smem[128 + k * 16 + j];
        y1[j] = fmaxf(v, 0.0f);
      }
      float z = smem[432];
#pragma unroll
      for (int k = 0; k < 16; ++k) z += y1[k] * smem[416 + k];
      reinterpret_cast<float*>(Out)[row] = fast_tanh(z);
    }
  } else {
    float pj[JPT];
    int jbase = sub * JPT;
#pragma unroll
    for (int jj = 0; jj < JPT; ++jj) {
      int j = jbase + jj;
      float v = 0.0f;
#pragma unroll
      for (int q8 = 0; q8 < 8; ++q8) v += h[q8] * smem[(krow + q8) * WST + j];
      pj[jj] = v;
    }
#pragma unroll
    for (int off = 1; off < L; off <<= 1) {
#pragma unroll
      for (int jj = 0; jj < JPT; ++jj) pj[jj] += __shfl_xor(pj[jj], off, 64);
    }
    if (ch8 == 0) {                  // pad rows write into pad hw slots (ok)
      _Float16* op = reinterpret_cast<_Float16*>(Out) + (size_t)br * DNEXT + jbase;
      if constexpr (JPT == 4) {
        uint2 u = make_uint2(pack2h(pj[0], pj[1]), pack2h(pj[2], pj[3]));
        *reinterpret_cast<uint2*>(op) = u;
      } else if constexpr (JPT == 2) {
        *reinterpret_cast<unsigned*>(op) = pack2h(pj[0], pj[1]);
      } else {
        op[0] = (_Float16)pj[0];
      }
    }
  }
}

// ---------------- launch ----------------
extern "C" void kernel_launch(void* const* d_in, const int* in_sizes, int n_in,
                              void* d_out, int out_size, void* d_ws, size_t ws_size,
                              hipStream_t stream) {
  const float* x   = (const float*)d_in[0];
  const int*  eidx = (const int*)d_in[1];
  const float* ew  = (const float*)d_in[2];
  const float* Wi  = (const float*)d_in[3];
  const float* bi  = (const float*)d_in[4];
  const float* Wc[12]; const float* bc[12];
  for (int i = 0; i < 12; ++i) {
    Wc[i] = (const float*)d_in[5 + 2 * i];
    bc[i] = (const float*)d_in[6 + 2 * i];
  }
  const float* Wm0 = (const float*)d_in[29]; const float* bm0 = (const float*)d_in[30];
  const float* Wm1 = (const float*)d_in[31]; const float* bm1 = (const float*)d_in[32];
  const float* Wf  = (const float*)d_in[33]; const float* bf  = (const float*)d_in[34];
  float* out = (float*)d_out;

  const int* src = eidx;        // edge_index[0]
  const int* dst = eidx + kE;   // edge_index[1]

  float* wsf = (float*)d_ws;
  size_t off = 0;
  float*     dinv = wsf + off;              off += PAD_N;
  float*     Weff = wsf + off;              off += 128 * 32;
  float*     beff = wsf + off;              off += 64;
  int*       cnt  = (int*)(wsf + off);      off += PAD_N;
  unsigned*  ecw  = (unsigned*)(wsf + off); off += (size_t)PAD_N * kCAP;  // 14.45 MB
  _Float16*  B16  = (_Float16*)(wsf + off); off += (size_t)PAD_N * 16;
  _Float16*  C16  = (_Float16*)(wsf + off); off += (size_t)PAD_N * 16;

  const int dgb  = PAD_N / 4;       // 12544 (deg + wscale grids, bucket rows)
  const int sb32 = PAD_N / 8;       // 6272  (2 rows/wave; mult of 8)
  const int sb16 = PAD_N / 16;      // 3136  (4 rows/wave; mult of 8)
  const int sb8  = PAD_N / 32;      // 1568  (8 rows/wave; mult of 8)

  prep<<<66, 256, 0, stream>>>(cnt, Wi, bi, Wc[0], Weff, beff);
  build_cnt_gemm0<<<NBG + 8 * E8B, 256, 0, stream>>>(src, dst, ew, cnt, ecw,
                                                     x, Weff, beff, B16, E4, kN);
  deg_dinv_wave<<<dgb, 256, 0, stream>>>(cnt, ecw, dinv);
  wscale_wave<<<dgb, 256, 0, stream>>>(cnt, ecw, dinv);

  spmm_fused<32, 32, false><<<sb32, 256, 0, stream>>>(B16, cnt, ecw, bc[0], Wc[1], C16, nullptr, nullptr, nullptr, nullptr, nullptr, nullptr, kN);
  spmm_fused<32, 32, false><<<sb32, 256, 0, stream>>>(C16, cnt, ecw, bc[1], Wc[2], B16, nullptr, nullptr, nullptr, nullptr, nullptr, nullptr, kN);
  spmm_fused<32, 32, false><<<sb32, 256, 0, stream>>>(B16, cnt, ecw, bc[2], Wc[3], C16, nullptr, nullptr, nullptr, nullptr, nullptr, nullptr, kN);
  spmm_fused<32, 16, false><<<sb32, 256, 0, stream>>>(C16, cnt, ecw, bc[3], Wc[4], B16, nullptr, nullptr, nullptr, nullptr, nullptr, nullptr, kN);
  spmm_fused<16, 16, false><<<sb16, 256, 0, stream>>>(B16, cnt, ecw, bc[4], Wc[5], C16, nullptr, nullptr, nullptr, nullptr, nullptr, nullptr, kN);
  spmm_fused<16, 16, false><<<sb16, 256, 0, stream>>>(C16, cnt, ecw, bc[5], Wc[6], B16, nullptr, nullptr, nullptr, nullptr, nullptr, nullptr, kN);
  spmm_fused<16, 16, false><<<sb16, 256, 0, stream>>>(B16, cnt, ecw, bc[6], Wc[7], C16, nullptr, nullptr, nullptr, nullptr, nullptr, nullptr, kN);
  spmm_fused<16, 8, false><<<sb16, 256, 0, stream>>>(C16, cnt, ecw, bc[7], Wc[8], B16, nullptr, nullptr, nullptr, nullptr, nullptr, nullptr, kN);
  spmm_fused<8, 8, false><<<sb8, 256, 0, stream>>>(B16, cnt, ecw, bc[8], Wc[9], C16, nullptr, nullptr, nullptr, nullptr, nullptr, nullptr, kN);
  spmm_fused<8, 8, false><<<sb8, 256, 0, stream>>>(C16, cnt, ecw, bc[9], Wc[10], B16, nullptr, nullptr, nullptr, nullptr, nullptr, nullptr, kN);
  spmm_fused<8, 8, false><<<sb8, 256, 0, stream>>>(B16, cnt, ecw, bc[10], Wc[11], C16, nullptr, nullptr, nullptr, nullptr, nullptr, nullptr, kN);
  spmm_fused<8, 0, true><<<sb8, 256, 0, stream>>>(C16, cnt, ecw, bc[11], nullptr, out, Wm0, bm0, Wm1, bm1, Wf, bf, kN);
}